// Round 9
// baseline (255.439 us; speedup 1.0000x reference)
//
#include <hip/hip_runtime.h>

#define BATCH 2
#define NPART 32768
#define GD 64
#define NVOX (BATCH * GD * GD * GD)   // 524288

typedef unsigned short ushortT;
typedef __attribute__((ext_vector_type(8))) short short8;
typedef __attribute__((ext_vector_type(16))) float float16;

__device__ __forceinline__ float poly6_c() {
    const double H9 = 1.0 / 35184372088832.0; // 0.03125^9 == 2^-45 (exact)
    return (float)(315.0 / (64.0 * 3.14159265358979323846 * H9));
}

__device__ __forceinline__ ushortT bf16_rne(float f) {
    unsigned int u = __float_as_uint(f);
    u = (u + 0x7fffu + ((u >> 16) & 1u)) >> 16;   // round-to-nearest-even
    return (ushortT)u;
}

__device__ __forceinline__ int imax(int a, int b) { return a > b ? a : b; }
__device__ __forceinline__ int imin(int a, int b) { return a < b ? a : b; }

// async global->LDS, 16 B per lane; LDS dest = wave-uniform base + lane*16
__device__ __forceinline__ void load_lds16(const void* g, void* l) {
    __builtin_amdgcn_global_load_lds(
        (const __attribute__((address_space(1))) void*)g,
        (__attribute__((address_space(3))) void*)l, 16, 0, 0);
}

// ---------------- zero ints (zguard + bin counts + cursors) ----------------
__global__ void zero_ints_kernel(int* __restrict__ p, int n) {
    int t = blockIdx.x * blockDim.x + threadIdx.x;
    if (t < n) p[t] = 0;
}

// ---------------- bin count: particle -> 2^3-cell bin histogram ----------------
__global__ __launch_bounds__(256) void bin_count_kernel(
    const float* __restrict__ locs, int* __restrict__ counts) {
    int t = blockIdx.x * blockDim.x + threadIdx.x;
    if (t >= BATCH * NPART) return;
    int b = t >> 15;
    int bx = ((int)floorf(locs[t * 3 + 0] * 64.0f)) >> 1;
    int by = ((int)floorf(locs[t * 3 + 1] * 64.0f)) >> 1;
    int bz = ((int)floorf(locs[t * 3 + 2] * 64.0f)) >> 1;
    atomicAdd(&counts[b * 32768 + ((bx * 32) + by) * 32 + bz], 1);
}

// ---------------- scan, level A: per-256-block exclusive scan ----------------
__global__ __launch_bounds__(256) void scanA_kernel(
    const int* __restrict__ counts, int* __restrict__ offsets,
    int* __restrict__ blockSum) {
    __shared__ int sh[256];
    int tid = threadIdx.x, g = blockIdx.x;        // 256 blocks x 256
    int v = counts[g * 256 + tid];
    sh[tid] = v;
    __syncthreads();
    for (int off = 1; off < 256; off <<= 1) {
        int u = (tid >= off) ? sh[tid - off] : 0;
        __syncthreads();
        sh[tid] += u;
        __syncthreads();
    }
    offsets[g * 256 + tid] = sh[tid] - v;         // exclusive
    if (tid == 255) blockSum[g] = sh[255];
}

// ---------------- scan, level B: add block prefixes ----------------
__global__ __launch_bounds__(256) void scanB_kernel(
    int* __restrict__ offsets, const int* __restrict__ blockSum) {
    __shared__ int sh[256];
    int tid = threadIdx.x, g = blockIdx.x;
    sh[tid] = (tid < g) ? blockSum[tid] : 0;
    __syncthreads();
    for (int off = 128; off > 0; off >>= 1) {
        if (tid < off) sh[tid] += sh[tid + off];
        __syncthreads();
    }
    offsets[g * 256 + tid] += sh[0];
    if (g == 255 && tid == 255) offsets[65536] = BATCH * NPART;  // sentinel
}

// ---------------- scatter particles into binned payload ----------------
__global__ __launch_bounds__(256) void bin_scatter_kernel(
    const float* __restrict__ locs, const float* __restrict__ data,
    const float* __restrict__ density, const int* __restrict__ offsets,
    int* __restrict__ cursor, float* __restrict__ payload) {
    int t = blockIdx.x * blockDim.x + threadIdx.x;
    if (t >= BATCH * NPART) return;
    int b = t >> 15;
    float px = locs[t * 3 + 0];
    float py = locs[t * 3 + 1];
    float pz = locs[t * 3 + 2];
    int bx = ((int)floorf(px * 64.0f)) >> 1;
    int by = ((int)floorf(py * 64.0f)) >> 1;
    int bz = ((int)floorf(pz * 64.0f)) >> 1;
    int bb = b * 32768 + ((bx * 32) + by) * 32 + bz;
    int slot = atomicAdd(&cursor[bb], 1);
    int idx = offsets[bb] + slot;
    float inv_d = 1.0f / density[t];
    float4 p0 = {px, py, pz, data[t * 4 + 0] * inv_d};
    float4 p1 = {data[t * 4 + 1] * inv_d, data[t * 4 + 2] * inv_d,
                 data[t * 4 + 3] * inv_d, 0.f};
    *(float4*)(payload + idx * 8)     = p0;
    *(float4*)(payload + idx * 8 + 4) = p1;
}

// ---------------- cell-owner gather splat: no atomics ----------------
__global__ __launch_bounds__(256) void splat_gather_kernel(
    const float* __restrict__ payload, const int* __restrict__ offsets,
    ushortT* __restrict__ g8) {
    __shared__ float plist[256 * 8];
    __shared__ int segS[36];
    __shared__ int segP[37];
    __shared__ int shTot[1];

    int wg = blockIdx.x;                          // 1024 = b*512 + sb
    int sb = wg & 511, b = wg >> 9;
    int X0 = (sb >> 6) * 8, Y0 = ((sb >> 3) & 7) * 8, Z0 = (sb & 7) * 8;
    int tid = threadIdx.x;

    int bxlo = imax(0, (X0 - 2) >> 1), bxhi = imin(31, (X0 + 9) >> 1);
    int bylo = imax(0, (Y0 - 2) >> 1), byhi = imin(31, (Y0 + 9) >> 1);
    int bzlo = imax(0, (Z0 - 2) >> 1), bzhi = imin(31, (Z0 + 9) >> 1);
    int ny = byhi - bylo + 1;
    int ns = (bxhi - bxlo + 1) * ny;
    if (tid < ns) {
        int bx = bxlo + tid / ny, by = bylo + tid % ny;
        int row = b * 32768 + (bx * 32 + by) * 32;
        int s = offsets[row + bzlo];
        int e = offsets[row + bzhi + 1];
        segS[tid] = s;
        segP[tid] = e - s;
    }
    __syncthreads();
    if (tid == 0) {
        int p = 0;
        for (int k = 0; k < ns; ++k) { int len = segP[k]; segP[k] = p; p += len; }
        segP[ns] = p;
        shTot[0] = p;
    }
    __syncthreads();

    const float step = 0.015625f;
    const float h2 = 0.03125f * 0.03125f;
    const float cc = poly6_c();
    int total = shTot[0];

    int l = tid & 63, w = tid >> 6;
    int cx = X0 + 4 * (w >> 1) + (l >> 4);
    int cy = Y0 + 4 * (w & 1) + ((l >> 2) & 3);
    int cz0 = Z0 + (l & 3);
    float xc  = ((float)cx  + 0.5f) * step;
    float yc  = ((float)cy  + 0.5f) * step;
    float zc0 = ((float)cz0 + 0.5f) * step;
    float zc1 = zc0 + 4.0f * step;

    float a00 = 0.f, a01 = 0.f, a02 = 0.f, a03 = 0.f;
    float a10 = 0.f, a11 = 0.f, a12 = 0.f, a13 = 0.f;

    int nchunks = (total + 255) >> 8;
    for (int ch = 0; ch < nchunks; ++ch) {
        __syncthreads();
        int jj = (ch << 8) + tid;
        if (jj < total) {
            int k = 0;
            while (jj >= segP[k + 1]) ++k;
            int idx = segS[k] + (jj - segP[k]);
            *(float4*)(plist + tid * 8)     = *(const float4*)(payload + idx * 8);
            *(float4*)(plist + tid * 8 + 4) = *(const float4*)(payload + idx * 8 + 4);
        }
        __syncthreads();
        int cnt = imin(256, total - (ch << 8));
        for (int p = 0; p < cnt; ++p) {
            float4 pa = *(const float4*)(plist + p * 8);     // broadcast read
            float dx = pa.x - xc, dy = pa.y - yc;
            float dxy2 = fmaf(dy, dy, dx * dx);
            if (!__any(dxy2 <= h2)) continue;                // wave-coherent skip
            float4 pv = *(const float4*)(plist + p * 8 + 4);
            float dz0 = pa.z - zc0;
            float d20 = fmaf(dz0, dz0, dxy2);
            float u0 = fmaxf(h2 - d20, 0.f);
            float w0 = (cc * u0) * (u0 * u0);
            a00 = fmaf(w0, pa.w, a00);
            a01 = fmaf(w0, pv.x, a01);
            a02 = fmaf(w0, pv.y, a02);
            a03 = fmaf(w0, pv.z, a03);
            float dz1 = pa.z - zc1;
            float d21 = fmaf(dz1, dz1, dxy2);
            float u1 = fmaxf(h2 - d21, 0.f);
            float w1 = (cc * u1) * (u1 * u1);
            a10 = fmaf(w1, pa.w, a10);
            a11 = fmaf(w1, pv.x, a11);
            a12 = fmaf(w1, pv.y, a12);
            a13 = fmaf(w1, pv.z, a13);
        }
    }

    size_t cellBase = (size_t)(((b * 64 + cx) * 64 + cy) * 64);
    short8 o;
    o[0] = (short)bf16_rne(a00); o[1] = (short)bf16_rne(a01);
    o[2] = (short)bf16_rne(a02); o[3] = (short)bf16_rne(a03);
    o[4] = 0; o[5] = 0; o[6] = 0; o[7] = 0;
    *(short8*)(g8 + (cellBase + cz0) * 8) = o;
    o[0] = (short)bf16_rne(a10); o[1] = (short)bf16_rne(a11);
    o[2] = (short)bf16_rne(a12); o[3] = (short)bf16_rne(a13);
    *(short8*)(g8 + (cellBase + cz0 + 4) * 8) = o;
}

// ---------------- fused weight repack into MFMA B-fragment order ----------------
// L0 (kt 0..13): k = kt*16+8q+j -> tap = k/8, ic = k%8 (CINP=8, I=4)
// L1/2/3 (27 kt per phase p): kt' = p*27+t ; ic = p*16 + q*8 + j ; tap = t
__global__ void repack_all_kernel(
    const float* __restrict__ W0, const float* __restrict__ W1,
    const float* __restrict__ W2, const float* __restrict__ W3,
    short* __restrict__ Bp) {
    int t = blockIdx.x * blockDim.x + threadIdx.x;
    if (t >= 176 * 512) return;
    int kt = t >> 9;
    int l = (t >> 3) & 63, j = t & 7;
    int n = l & 31, q = l >> 5;
    float v = 0.f;
    if (kt < 14) {
        int k = kt * 16 + 8 * q + j;
        int tap = k / 8, ic = k - tap * 8;
        if (tap < 27 && ic < 4) v = W0[(n * 4 + ic) * 27 + tap];
    } else {
        int rem = kt - 14;
        const float* W; int O;
        if (rem < 54)       { W = W1; O = 32; }
        else if (rem < 108) { W = W2; O = 32; rem -= 54; }
        else                { W = W3; O = 4;  rem -= 108; }
        int p = rem / 27, tap = rem - p * 27;
        int ic = p * 16 + q * 8 + j;
        if (n < O) v = W[(n * 32 + ic) * 27 + tap];
    }
    Bp[t] = (short)bf16_rne(v);
}

// ---------------- MFMA implicit-GEMM 3x3x3 conv, K-phased staging ----------
// WG owns 2x4 columns x 32-z half; wave owns 2 adjacent-y cols (2 acc).
// ICG=4: two phases over icg halves; LDS = 4x6 cols x 2 icg x 34 z = 26112 B
// -> 6 WG/CU. ICG=1: single phase, 13056 B. Staging via global_load_lds.
template <int ICG, int KT, bool FINAL>
__global__ __launch_bounds__(256) void mfma_conv_kernel(
    const ushortT* __restrict__ in, const short* __restrict__ Bpack,
    const float* __restrict__ bias, const float* __restrict__ alpha,
    const float* __restrict__ zguard, void* __restrict__ outv) {
    constexpr int CIN = ICG * 8;
    constexpr int NPH  = (ICG == 4) ? 2 : 1;       // staging phases
    constexpr int ICGH = (ICG == 4) ? 2 : 1;       // icg groups per phase
    constexpr int NCHH = 24 * ICGH * 34;           // 16 B chunks per phase
    constexpr int KTH  = KT / NPH;
    __shared__ short lds[NCHH * 8];
    // XCD swizzle: contiguous slab per XCD
    int wg = ((blockIdx.x & 7) << 8) | (blockIdx.x >> 3);   // 2048
    int zh = wg & 1, yq = (wg >> 1) & 15, xp = (wg >> 5) & 31, b = wg >> 10;
    int X0 = xp * 2, Y0 = yq * 4, Z0 = zh * 32;
    int tid = threadIdx.x;

    const ushortT* inb = in + (size_t)b * (64 * 64 * 64 * CIN);

    int l = tid & 63, w = tid >> 6;
    int wx = w >> 1;                               // owned x in 2
    int cyA = (w & 1) * 2, cyB = cyA + 1;          // owned y pair in 4
    int n = l & 31, q = l >> 5;

    float bval = FINAL ? (n < 4 ? bias[n] : 0.f) : bias[n];
    float16 accA, accB;
#pragma unroll
    for (int r = 0; r < 16; ++r) { accA[r] = bval; accB[r] = bval; }

    const short* bp = Bpack + (size_t)l * 8;
    int laneZ = (l & 31) * 8;                      // z-row offset (shorts)

#pragma unroll
    for (int p = 0; p < NPH; ++p) {
        if (p) __syncthreads();                    // all reads of prev half done
        // ---- stage phase p: halo 4x6 cols x ICGH icg x 34 z ----
#pragma unroll
        for (int it = 0; it < (NCHH + 255) / 256; ++it) {
            int ccid = it * 256 + tid;
            if (ccid < NCHH) {
                int col  = ccid / (ICGH * 34);
                int rem  = ccid - col * (ICGH * 34);
                int icgL = rem / 34;
                int zi   = rem - icgL * 34;
                int gx = X0 + col / 6 - 1;
                int gy = Y0 + col % 6 - 1;
                int gz = Z0 + zi - 1;
                const void* src = (const void*)zguard;
                if ((unsigned)gx < 64u && (unsigned)gy < 64u && (unsigned)gz < 64u)
                    src = (const void*)(inb + ((size_t)(((gx * 64) + gy) * 64 + gz)) * CIN
                                        + (p * ICGH + icgL) * 8);
                load_lds16(src, (void*)(lds + ccid * 8));
            }
        }
        __syncthreads();   // drains vmcnt (global_load_lds) + barrier

        const short* bph = bp + (size_t)(p * KTH) * 512;
        short8 bf[4];
#pragma unroll
        for (int i = 0; i < 4; ++i) bf[i] = *(const short8*)(bph + i * 512);

#pragma unroll
        for (int t = 0; t < KTH; ++t) {
            short8 bcur = bf[t & 3];
            if (t + 4 < KTH) bf[t & 3] = *(const short8*)(bph + (t + 4) * 512);
            int aofsA, aofsB;
            if constexpr (ICG == 1) {
                int tap0 = t * 2, tap1 = t * 2 + 1;
                if (tap1 > 26) tap1 = 26;          // B is zero there
                int dx0 = tap0 / 9, r0 = tap0 - dx0 * 9, dy0 = r0 / 3, dz0 = r0 - dy0 * 3;
                int dx1 = tap1 / 9, r1 = tap1 - dx1 * 9, dy1 = r1 / 3, dz1 = r1 - dy1 * 3;
                int cA0 = (((wx + dx0) * 6 + (cyA + dy0)) * 34 + dz0) * 8;
                int cA1 = (((wx + dx1) * 6 + (cyA + dy1)) * 34 + dz1) * 8;
                int cB0 = (((wx + dx0) * 6 + (cyB + dy0)) * 34 + dz0) * 8;
                int cB1 = (((wx + dx1) * 6 + (cyB + dy1)) * 34 + dz1) * 8;
                aofsA = q ? cA1 : cA0;
                aofsB = q ? cB1 : cB0;
            } else {
                int dx = t / 9, rr = t - dx * 9, dy = rr / 3, dz = rr - dy * 3;
                aofsA = ((((wx + dx) * 6 + (cyA + dy)) * 2 + q) * 34 + dz) * 8;
                aofsB = ((((wx + dx) * 6 + (cyB + dy)) * 2 + q) * 34 + dz) * 8;
            }
            short8 afragA = *(const short8*)(lds + aofsA + laneZ);
            short8 afragB = *(const short8*)(lds + aofsB + laneZ);
            accA = __builtin_amdgcn_mfma_f32_32x32x16_bf16(afragA, bcur, accA, 0, 0, 0);
            accB = __builtin_amdgcn_mfma_f32_32x32x16_bf16(afragB, bcur, accB, 0, 0, 0);
        }
    }

    size_t baseA = (size_t)(((b * 64 + X0 + wx) * 64 + (Y0 + cyA)) * 64) + Z0;
    size_t baseB = (size_t)(((b * 64 + X0 + wx) * 64 + (Y0 + cyB)) * 64) + Z0;
    if (FINAL) {
        float* out = (float*)outv;
        if (n < 4) {
#pragma unroll
            for (int r = 0; r < 16; ++r) {
                int z = (r & 3) + 8 * (r >> 2) + 4 * q;
                out[(baseA + z) * 4 + n] = accA[r];
                out[(baseB + z) * 4 + n] = accB[r];
            }
        }
    } else {
        float a = alpha[0];
        ushortT* out = (ushortT*)outv;
#pragma unroll
        for (int r = 0; r < 16; ++r) {
            int z = (r & 3) + 8 * (r >> 2) + 4 * q;
            float vA = accA[r];
            vA = vA >= 0.f ? vA : a * vA;
            out[(baseA + z) * 32 + n] = bf16_rne(vA);
            float vB = accB[r];
            vB = vB >= 0.f ? vB : a * vB;
            out[(baseB + z) * 32 + n] = bf16_rne(vB);
        }
    }
}

// ---------------- grid2particles (trilinear gather, fp32 grid) ----------------
__global__ __launch_bounds__(256) void gather_kernel(
    const float* __restrict__ grid, const float* __restrict__ locs,
    float* __restrict__ out) {
    int t = blockIdx.x * blockDim.x + threadIdx.x;
    if (t >= BATCH * NPART) return;
    int b = t >> 15;

    float px = locs[t * 3 + 0] * 64.0f - 0.5f;
    float py = locs[t * 3 + 1] * 64.0f - 0.5f;
    float pz = locs[t * 3 + 2] * 64.0f - 0.5f;
    int ix = (int)floorf(px);
    int iy = (int)floorf(py);
    int iz = (int)floorf(pz);
    float fx = px - (float)ix;
    float fy = py - (float)iy;
    float fz = pz - (float)iz;

    const float* gb = grid + (size_t)b * GD * GD * GD * 4;
    float o0 = 0.f, o1 = 0.f, o2 = 0.f, o3 = 0.f;

#pragma unroll
    for (int dx = 0; dx < 2; ++dx) {
        int x = ix + dx;
        if ((unsigned)x > 63u) continue;
        float wx = dx ? fx : 1.0f - fx;
#pragma unroll
        for (int dy = 0; dy < 2; ++dy) {
            int y = iy + dy;
            if ((unsigned)y > 63u) continue;
            float wy = dy ? fy : 1.0f - fy;
#pragma unroll
            for (int dz = 0; dz < 2; ++dz) {
                int z = iz + dz;
                if ((unsigned)z > 63u) continue;
                float wz = dz ? fz : 1.0f - fz;
                float w = wx * wy * wz;
                const float4 g = *(const float4*)(gb + (size_t)(((x * GD) + y) * GD + z) * 4);
                o0 += w * g.x; o1 += w * g.y; o2 += w * g.z; o3 += w * g.w;
            }
        }
    }
    out[t * 4 + 0] = o0;
    out[t * 4 + 1] = o1;
    out[t * 4 + 2] = o2;
    out[t * 4 + 3] = o3;
}

extern "C" void kernel_launch(void* const* d_in, const int* in_sizes, int n_in,
                              void* d_out, int out_size, void* d_ws, size_t ws_size,
                              hipStream_t stream) {
    const float* locs    = (const float*)d_in[0];
    const float* data    = (const float*)d_in[1];
    const float* density = (const float*)d_in[2];
    const float* W0 = (const float*)d_in[3];
    const float* b0 = (const float*)d_in[4];
    const float* W1 = (const float*)d_in[5];
    const float* b1 = (const float*)d_in[6];
    const float* W2 = (const float*)d_in[7];
    const float* b2 = (const float*)d_in[8];
    const float* W3 = (const float*)d_in[9];
    const float* b3 = (const float*)d_in[10];
    const float* a0 = (const float*)d_in[11];
    const float* a1 = (const float*)d_in[12];
    const float* a2 = (const float*)d_in[13];
    float* out = (float*)d_out;

    char* ws = (char*)d_ws;
    ushortT* g8  = (ushortT*)(ws);                       // 8 MB bf16 8ch
    ushortT* gA  = (ushortT*)(ws + 8388608);             // 33.5 MB bf16 32ch
    ushortT* gB  = (ushortT*)(ws + 41943040);            // 33.5 MB bf16 32ch
    float*  gF   = (float*)(ws + 75497472);              // 8 MB fp32 4ch
    short*  Bp   = (short*)(ws + 83886080);              // 176*512*2 = 180224 B
    short*  Bp0  = Bp;                                   // kt 0..13
    short*  Bp1  = Bp + 14 * 512;                        // kt 14..67
    short*  Bp2  = Bp + 68 * 512;                        // kt 68..121
    short*  Bp3  = Bp + 122 * 512;                       // kt 122..175
    float* zguard   = (float*)(ws + 84066240);           // 64 B zeros (16 ints)
    int*   counts   = (int*)(ws + 84066304);             // 65536 ints
    int*   cursor   = (int*)(ws + 84328448);             // 65536 ints
    int*   offsets  = (int*)(ws + 84590592);             // 65537 ints
    int*   blockSum = (int*)(ws + 84852752);             // 256 ints
    float* payload  = (float*)(ws + 84853888);           // 65536*8 floats = 2 MB

    // ---- zero zguard + counts + cursor (contiguous from zguard) ----
    zero_ints_kernel<<<(131088 + 255) / 256, 256, 0, stream>>>((int*)zguard, 131088);
    bin_count_kernel<<<(BATCH * NPART) / 256, 256, 0, stream>>>(locs, counts);
    scanA_kernel<<<256, 256, 0, stream>>>(counts, offsets, blockSum);
    scanB_kernel<<<256, 256, 0, stream>>>(offsets, blockSum);
    bin_scatter_kernel<<<(BATCH * NPART) / 256, 256, 0, stream>>>(
        locs, data, density, offsets, cursor, payload);

    // ---- weight repack (fused) ----
    repack_all_kernel<<<(176 * 512 + 255) / 256, 256, 0, stream>>>(W0, W1, W2, W3, Bp);

    // ---- particles -> bf16 grid (cell-owner gather, no atomics) ----
    splat_gather_kernel<<<BATCH * 512, 256, 0, stream>>>(payload, offsets, g8);

    // ---- conv chain ----
    const int CGRID = 2048;   // 2 b x 32 xp x 16 yq x 2 zh
    mfma_conv_kernel< 1, 14, false><<<CGRID, 256, 0, stream>>>(g8, Bp0, b0, a0, zguard, gA);
    mfma_conv_kernel< 4, 54, false><<<CGRID, 256, 0, stream>>>(gA, Bp1, b1, a1, zguard, gB);
    mfma_conv_kernel< 4, 54, false><<<CGRID, 256, 0, stream>>>(gB, Bp2, b2, a2, zguard, gA);
    mfma_conv_kernel< 4, 54, true ><<<CGRID, 256, 0, stream>>>(gA, Bp3, b3, b3, zguard, gF);

    // ---- grid -> particles ----
    gather_kernel<<<(BATCH * NPART) / 256, 256, 0, stream>>>(gF, locs, out);
}